// Round 10
// baseline (685.224 us; speedup 1.0000x reference)
//
#include <hip/hip_runtime.h>
#include <hip/hip_bf16.h>

// Decoder: T=32, B=64, S=256, DEC=ENC=ATT=WV=512, V=32000, POOL=2
// Round 10: R9 with the P2 bank-conflict fixed. R9's P2 read 4 ks-slices at
// stride 256B (= bank-row multiple) -> 4-way same-bank conflict on all 64
// loads. Fix: +1-uint pad per 64-uint slice (store tid+(tid>>6), read ks*65+j)
// -> 4 slices in 4 distinct banks, each 16-lane broadcast.
//
// ws layout (float units):
//   preb     ushort[64][256][512] @ 0         (4194304 f)
//   gxe      f32  [2048][1536]    @ 4194304   (3145728)
//   h_hist   f32  [32][64][512]   @ 7340032   (1048576)
//   ctx_hist f32  [32][64][512]   @ 8388608   (1048576)
//   pe_buf   f32  [32][64][4][256]@ 9437184   (2097152)
//   Wpk      uint [786432]        @ 11534336  (786432)
//   WqT      uint [256][512]      @ 12320768  (131072)
//   hswz     ushort[32][64][512]  @ 12451840  (524288 f)   swizzled bf16 h
//   cswz     ushort[32][64][512]  @ 12976128  (524288 f)   swizzled bf16 ctx
//   counters uint [4096]          @ 13500416  (4096)

typedef unsigned int uint;
typedef unsigned short ushort;
typedef __attribute__((ext_vector_type(8))) short s8v;   // 8 bf16
typedef __attribute__((ext_vector_type(4))) float f4v;   // 4 f32

#define DD 512

__device__ __forceinline__ float sigmf(float x) { return 1.0f / (1.0f + __expf(-x)); }
__device__ __forceinline__ float tanh_fast(float x) {
    float e = __expf(2.0f * x);
    return 1.0f - 2.0f / (e + 1.0f);
}
__device__ __forceinline__ ushort f2bf(float f) {
    uint b = __float_as_uint(f);
    return (ushort)((b + 0x7FFFu + ((b >> 16) & 1u)) >> 16);
}
__device__ __forceinline__ uint pk2(float a, float b) {
    return (uint)f2bf(a) | ((uint)f2bf(b) << 16);
}
__device__ __forceinline__ float bfl(uint u) { return __uint_as_float(u << 16); }
__device__ __forceinline__ float bfh(uint u) { return __uint_as_float(u & 0xFFFF0000u); }
__device__ __forceinline__ f4v MFMA(s8v a, s8v b, f4v c) {
    return __builtin_amdgcn_mfma_f32_16x16x32_bf16(a, b, c, 0, 0, 0);
}

// Flag-slot barrier (relaxed, no cache maintenance; see R7/R8 rationale).
__device__ __forceinline__ void flag_bar(uint* arr, uint* rel, int member,
                                         int nmem, uint tag) {
    __syncthreads();
    const int tid = threadIdx.x;
    if (tid == 0) {
        asm volatile("s_waitcnt vmcnt(0) lgkmcnt(0)" ::: "memory");
        __hip_atomic_store(arr + member, tag, __ATOMIC_RELAXED,
                           __HIP_MEMORY_SCOPE_AGENT);
    }
    if (member == 0) {
        if (tid > 0 && tid < nmem) {
            while (__hip_atomic_load(arr + tid, __ATOMIC_RELAXED,
                                     __HIP_MEMORY_SCOPE_AGENT) < tag) {}
        }
        if (tid == 0)
            __hip_atomic_store(rel, tag, __ATOMIC_RELAXED,
                               __HIP_MEMORY_SCOPE_AGENT);
    } else {
        if (tid == 0) {
            while (__hip_atomic_load(rel, __ATOMIC_RELAXED,
                                     __HIP_MEMORY_SCOPE_AGENT) < tag) {}
        }
    }
    __syncthreads();
}

// ================= unified MFMA GEMM: C[M,N] = A[M,K] @ B[N,K]^T + bias =======
template <int MODE>
__global__ __launch_bounds__(256) void mgemm(
    const float* __restrict__ A0, const float* __restrict__ A1,
    const float* __restrict__ A2, const int* __restrict__ ids,
    const float* __restrict__ Bm, const float* __restrict__ bias,
    void* __restrict__ Cout, int ldb, int K)
{
    __shared__ __align__(16) ushort Ab[64 * 32];
    __shared__ __align__(16) ushort Bb[64 * 32];
    __shared__ int rid[64];
    const int tid = threadIdx.x;
    const int m0 = blockIdx.x * 64, n0 = blockIdx.y * 64;
    if (MODE != 0 && tid < 64) rid[tid] = ids[m0 + tid];
    const int lane = tid & 63;
    const int w = tid >> 6;
    const int srow = tid >> 2, sc = tid & 3;
    f4v acc[4];
#pragma unroll
    for (int mt = 0; mt < 4; ++mt) acc[mt] = (f4v){0.f, 0.f, 0.f, 0.f};

    for (int k0 = 0; k0 < K; k0 += 32) {
        __syncthreads();
        {
            const float* ap;
            int m = m0 + srow;
            if (MODE == 0) {
                ap = A0 + (size_t)(m & 255) * 32768 + (size_t)(m >> 8) * 512 + k0 + sc * 8;
            } else if (MODE == 1) {
                ap = A0 + (size_t)rid[srow] * 512 + k0 + sc * 8;
            } else {
                if (k0 < 512)       ap = A0 + (size_t)rid[srow] * 512 + k0 + sc * 8;
                else if (k0 < 1024) ap = A1 + (size_t)m * 512 + (k0 - 512) + sc * 8;
                else                ap = A2 + (size_t)m * 512 + (k0 - 1024) + sc * 8;
            }
            float4 v0 = *(const float4*)ap;
            float4 v1 = *(const float4*)(ap + 4);
            uint4 pa;
            pa.x = pk2(v0.x, v0.y); pa.y = pk2(v0.z, v0.w);
            pa.z = pk2(v1.x, v1.y); pa.w = pk2(v1.z, v1.w);
            *(uint4*)&Ab[srow * 32 + ((sc ^ (srow & 3)) << 3)] = pa;
            const float* bp = Bm + (size_t)(n0 + srow) * ldb + k0 + sc * 8;
            float4 w0 = *(const float4*)bp;
            float4 w1 = *(const float4*)(bp + 4);
            uint4 pb;
            pb.x = pk2(w0.x, w0.y); pb.y = pk2(w0.z, w0.w);
            pb.z = pk2(w1.x, w1.y); pb.w = pk2(w1.z, w1.w);
            *(uint4*)&Bb[srow * 32 + ((sc ^ (srow & 3)) << 3)] = pb;
        }
        __syncthreads();
        int rr = lane & 15, kc = lane >> 4;
        s8v bf = *(const s8v*)&Bb[(w * 16 + rr) * 32 + ((kc ^ (rr & 3)) << 3)];
#pragma unroll
        for (int mt = 0; mt < 4; ++mt) {
            s8v af = *(const s8v*)&Ab[(mt * 16 + rr) * 32 + ((kc ^ (rr & 3)) << 3)];
            acc[mt] = MFMA(af, bf, acc[mt]);
        }
    }
    float bv = bias[n0 + w * 16 + (lane & 15)];
#pragma unroll
    for (int mt = 0; mt < 4; ++mt) {
#pragma unroll
        for (int r2 = 0; r2 < 4; ++r2) {
            int m = m0 + mt * 16 + (lane >> 4) * 4 + r2;
            int n = n0 + w * 16 + (lane & 15);
            float v = acc[mt][r2] + bv;
            if (MODE == 0) {
                ((ushort*)Cout)[(size_t)m * 512 + n] = f2bf(v);
            } else if (MODE == 1) {
                ((float*)Cout)[(size_t)m * 1536 + n] = v;
            } else {
                float vm = fmaxf(v, __shfl_xor(v, 1));
                if (!(lane & 1)) ((float*)Cout)[(size_t)m * 256 + (n >> 1)] = vm;
            }
        }
    }
}

// ================= weight prep: Wpk (B-fragment order) + WqT ==================
__global__ __launch_bounds__(512) void wprep2(
    const float* __restrict__ W_ih, const float* __restrict__ W_hh,
    const float* __restrict__ W_q,
    uint* __restrict__ Wpk, uint* __restrict__ WqT)
{
    int id = blockIdx.x * 512 + threadIdx.x;
    if (id < 786432) {
        int l4 = id & 255;
        int chunk = id >> 8;
        int g = chunk % 3;
        int t2 = chunk / 3;
        int ks = t2 & 15;
        int mat = (t2 >> 4) & 1;
        int u = t2 >> 5;
        int lane = l4 >> 2, e2 = l4 & 3;
        int n = g * 512 + u * 16 + (lane & 15);
        int k = ks * 32 + ((lane >> 4) << 3) + e2 * 2;
        float w0, w1;
        if (mat == 0) {
            w0 = W_ih[(size_t)n * 1024 + 512 + k];
            w1 = W_ih[(size_t)n * 1024 + 512 + k + 1];
        } else {
            w0 = W_hh[(size_t)n * 512 + k];
            w1 = W_hh[(size_t)n * 512 + k + 1];
        }
        Wpk[id] = pk2(w0, w1);
    } else if (id < 917504) {
        int rid2 = id - 786432;
        int kp = rid2 >> 9, a = rid2 & 511;
        WqT[rid2] = pk2(W_q[(size_t)a * 512 + 2 * kp], W_q[(size_t)a * 512 + 2 * kp + 1]);
    }
}

// ================= persistent 32-step kernel ==================================
// 256 blocks x 512 thr (8 waves), 1/CU. q = blk>>6, b = blk&63, r = b&7,
// u = ((b>>3)<<2)|q. Group = 32 blocks same r (same XCD); cluster = 4 q's of b.
// hswz/cswz: bf16, chunk-swizzled: buf[b][ ((d>>3)^(b>>3))*8 + (d&7) ].
__global__ __launch_bounds__(512, 1) void k_steps(
    const float* __restrict__ gxe, const float* __restrict__ hidden,
    const float* __restrict__ init_att, const float* __restrict__ context,
    const float* __restrict__ mask, const float* __restrict__ v_att,
    const float* __restrict__ b_hh, const ushort* __restrict__ preb,
    const uint* __restrict__ Wpk, const uint* __restrict__ WqT,
    float* __restrict__ h_hist, float* __restrict__ ctx_hist,
    ushort* __restrict__ hswz, ushort* __restrict__ cswz,
    float* __restrict__ pe_buf, uint* __restrict__ cnt,
    float* __restrict__ cout)
{
    __shared__ __align__(16) ushort preT[256 * 128];   // 64KB [s][a-slice], swizzled
    __shared__ __align__(16) ushort ctxT[256 * 128];   // 64KB [s][e-slice], linear
    __shared__ __align__(16) float scr[6144];          // 24KB multiplexed
    __shared__ float smask[256];
    __shared__ float svatt[128];

    const int tid = threadIdx.x;
    const int blk = blockIdx.x;
    const int q = blk >> 6;
    const int b = blk & 63;
    const int r = b & 7;
    const int u = ((b >> 3) << 2) | q;
    const int lane = tid & 63;
    const int wid = __builtin_amdgcn_readfirstlane(tid >> 6);

    uint* garr = cnt + r * 64;
    uint* grel = cnt + 512 + r * 16;
    uint* carr = cnt + 1024 + b * 8;
    uint* crel = cnt + 2048 + b * 16;

    // ---- one-time staging: pre(bf16) + context(->bf16) into LDS ----
#pragma unroll
    for (int cc = 0; cc < 8; ++cc) {
        int cid = tid * 8 + cc;
        int s = cid >> 4, ch = cid & 15;
        int sw = (s ^ (s >> 3)) & 7;
        uint4 pv = *(const uint4*)(preb + ((size_t)(b * 256 + s)) * 512 + q * 128 + ch * 8);
        *(uint4*)&preT[s * 128 + ((ch ^ sw) << 3)] = pv;
        const float* cp = context + ((size_t)s * 64 + b) * 512 + q * 128 + ch * 8;
        float4 c0 = *(const float4*)cp;
        float4 c1 = *(const float4*)(cp + 4);
        uint4 cv;
        cv.x = pk2(c0.x, c0.y); cv.y = pk2(c0.z, c0.w);
        cv.z = pk2(c1.x, c1.y); cv.w = pk2(c1.z, c1.w);
        *(uint4*)&ctxT[s * 128 + ch * 8] = cv;
    }
    if (tid < 256) smask[tid] = mask[b * 256 + tid];
    else if (tid < 384) svatt[tid - 256] = v_att[q * 128 + (tid - 256)];

    // ---- register-resident weights (loop-invariant) ----
    const int mat_w = wid >> 2, kw = wid & 3;   // wave role in P1
    s8v wr0[4], wr1[4], wr2[4];
#pragma unroll
    for (int s = 0; s < 4; ++s) {
        int ks = kw * 4 + s;
        const uint* wb = Wpk + ((((u * 2 + mat_w) * 16 + ks) * 3) << 8) + (lane << 2);
        wr0[s] = *(const s8v*)(wb);
        wr1[s] = *(const s8v*)(wb + 256);
        wr2[s] = *(const s8v*)(wb + 512);
    }
    // P2 weights: (a, ks) lane map, swizzled-h index baked in
    const int a_p2 = tid >> 2;       // 0..127
    const int ks_p2 = tid & 3;       // 0..3
    const int rowb = b >> 3;
    uint wqreg[64];
#pragma unroll
    for (int j = 0; j < 64; ++j) {
        int uidx = ks_p2 * 64 + j;
        int swc = uidx >> 2, p = uidx & 3;
        int kp = ((swc ^ rowb) << 2) + p;
        wqreg[j] = WqT[(size_t)kp * 512 + q * 128 + a_p2];
    }

    const int bloc = tid >> 4, jj = tid & 15;
    int bb_c = 0, d_c = 0, eidx = 0;
    size_t hsw_off = 0;
    float bh0 = 0.f, bh1 = 0.f, bh2 = 0.f;
    if (tid < 128) {
        bb_c = r + bloc * 8;
        d_c = u * 16 + jj;
        eidx = ((jj + ((bloc >> 2) << 4)) << 2) + (bloc & 3);
        hsw_off = (size_t)bb_c * 512 + (((d_c >> 3) ^ (bb_c >> 3)) << 3) + (d_c & 7);
        bh0 = b_hh[d_c]; bh1 = b_hh[512 + d_c]; bh2 = b_hh[1024 + d_c];
    }

    for (int t = 0; t < 32; ++t) {
        // ---- prefetch critical-path globals (overlap with P1a/P1b) ----
        float gx0 = 0.f, gx1 = 0.f, gx2 = 0.f, hpv = 0.f;
        if (tid < 128) {
            const float* gp = gxe + ((size_t)t * 64 + bb_c) * 1536 + d_c;
            gx0 = gp[0]; gx1 = gp[512]; gx2 = gp[1024];
            const float* hp = t ? (h_hist + (size_t)(t - 1) * 32768) : hidden;
            hpv = hp[(size_t)bb_c * 512 + d_c];
        }

        // ---- P1a: stage x (ctx_prev, h_prev for group's 8 b's) -> LDS bf16 ----
        __syncthreads();
        if (t == 0) {
            int c2 = tid & 31, row = (tid >> 5) & 7, mat = tid >> 8;
            const float* src = mat ? hidden : init_att;
            int bb = r + row * 8;
            const float* sp = src + (size_t)bb * 512 + c2 * 16;
            float4 v0 = *(const float4*)sp, v1 = *(const float4*)(sp + 4);
            float4 v2 = *(const float4*)(sp + 8), v3 = *(const float4*)(sp + 12);
            uint4 p0, p1;
            p0.x = pk2(v0.x, v0.y); p0.y = pk2(v0.z, v0.w);
            p0.z = pk2(v1.x, v1.y); p0.w = pk2(v1.z, v1.w);
            p1.x = pk2(v2.x, v2.y); p1.y = pk2(v2.z, v2.w);
            p1.z = pk2(v3.x, v3.y); p1.w = pk2(v3.z, v3.w);
            char* xb = (char*)scr + mat * 8192 + row * 1024;
            int c0 = c2 * 2;
            *(uint4*)(xb + ((c0 ^ row) << 4)) = p0;
            *(uint4*)(xb + (((c0 + 1) ^ row) << 4)) = p1;
        } else {
            // swizzle baked into hswz/cswz: plain linear uint4 copies
            int row = tid >> 6, sc = tid & 63;
            size_t goff = (size_t)(t - 1) * 16384 + (size_t)(r + row * 8) * 256 + sc * 4;
            uint4 va = ((const uint4*)cswz)[goff >> 2];
            uint4 vb = ((const uint4*)hswz)[goff >> 2];
            ((uint4*)scr)[tid] = va;
            ((uint4*)scr)[512 + tid] = vb;
        }
        __syncthreads();
        // ---- P1b: MFMA with register weights ----
        f4v ac0 = (f4v){0.f, 0.f, 0.f, 0.f};
        f4v ac1 = ac0, ac2 = ac0;
        {
            const char* xbase = (const char*)scr + mat_w * 8192 + (lane & 15) * 1024;
            int rsw = (lane & 15) & 7;
#pragma unroll
            for (int s = 0; s < 4; ++s) {
                int ch = kw * 16 + s * 4 + (lane >> 4);
                s8v af = *(const s8v*)(xbase + ((ch ^ rsw) << 4));
                ac0 = MFMA(af, wr0[s], ac0);
                ac1 = MFMA(af, wr1[s], ac1);
                ac2 = MFMA(af, wr2[s], ac2);
            }
        }
        __syncthreads();   // all waves done reading x-stage; rb aliases it
        {
            f4v* rb = (f4v*)scr;
            rb[((mat_w * 3 + 0) * 4 + kw) * 64 + lane] = ac0;
            rb[((mat_w * 3 + 1) * 4 + kw) * 64 + lane] = ac1;
            rb[((mat_w * 3 + 2) * 4 + kw) * 64 + lane] = ac2;
        }
        __syncthreads();
        // ---- P1c: reduce + gates (128 threads: 8 b x 16 d) ----
        if (tid < 128) {
            float AX[3], AH[3];
#pragma unroll
            for (int g = 0; g < 3; ++g) {
                float sx = 0.f, sh = 0.f;
#pragma unroll
                for (int kw2 = 0; kw2 < 4; ++kw2) {
                    sx += scr[((0 + g) * 4 + kw2) * 256 + eidx];
                    sh += scr[((3 + g) * 4 + kw2) * 256 + eidx];
                }
                AX[g] = sx;
                AH[g] = sh;
            }
            AX[0] += gx0; AX[1] += gx1; AX[2] += gx2;
            AH[0] += bh0; AH[1] += bh1; AH[2] += bh2;
            float rr = sigmf(AX[0] + AH[0]);
            float zz = sigmf(AX[1] + AH[1]);
            float nn = tanh_fast(AX[2] + rr * AH[2]);
            float hval = (1.0f - zz) * nn + zz * hpv;
            h_hist[(size_t)t * 32768 + (size_t)bb_c * 512 + d_c] = hval;
            hswz[(size_t)t * 32768 + hsw_off] = f2bf(hval);
        }
        flag_bar(garr, grel, u, 32, (uint)(t * 4 + 1));

        // ---- P2: target a-slice q*128 from bf16 h[b] (register Wq, shfl red) --
        // stage h with +1-uint pad per 64-uint slice -> 4 ks-slices hit 4 banks
        {
            uint* scr_u = (uint*)scr;
            if (tid < 256)
                scr_u[tid + (tid >> 6)] =
                    ((const uint*)(hswz + (size_t)t * 32768))[b * 256 + tid];
        }
        __syncthreads();
        {
            const uint* hsrc = (const uint*)scr + ks_p2 * 65;
            float a0 = 0.f, a1 = 0.f, a2 = 0.f, a3 = 0.f;
#pragma unroll
            for (int j = 0; j < 64; j += 4) {
                uint h0 = hsrc[j], h1 = hsrc[j + 1], h2 = hsrc[j + 2], h3 = hsrc[j + 3];
                uint w0 = wqreg[j], w1 = wqreg[j + 1], w2 = wqreg[j + 2], w3 = wqreg[j + 3];
                a0 = fmaf(bfl(w0), bfl(h0), fmaf(bfh(w0), bfh(h0), a0));
                a1 = fmaf(bfl(w1), bfl(h1), fmaf(bfh(w1), bfh(h1), a1));
                a2 = fmaf(bfl(w2), bfl(h2), fmaf(bfh(w2), bfh(h2), a2));
                a3 = fmaf(bfl(w3), bfl(h3), fmaf(bfh(w3), bfh(h3), a3));
            }
            float acc = (a0 + a1) + (a2 + a3);
            acc += __shfl_xor(acc, 1);
            acc += __shfl_xor(acc, 2);
            if (ks_p2 == 0) scr[1024 + a_p2] = acc;
        }
        __syncthreads();

        // ---- P3: partial energy over a-slice, all 256 s ----
        {
            int s = tid & 255, hf = tid >> 8;
            int sw = (s ^ (s >> 3)) & 7;
            float acc0 = 0.f, acc1 = 0.f;
#pragma unroll
            for (int c8 = 0; c8 < 8; ++c8) {
                int ch = hf * 8 + c8;
                uint4 pv = *(const uint4*)&preT[s * 128 + ((ch ^ sw) << 3)];
                int ab = ch * 8;
                acc0 += svatt[ab + 0] * tanh_fast(bfl(pv.x) + scr[1024 + ab + 0]);
                acc1 += svatt[ab + 1] * tanh_fast(bfh(pv.x) + scr[1024 + ab + 1]);
                acc0 += svatt[ab + 2] * tanh_fast(bfl(pv.y) + scr[1024 + ab + 2]);
                acc1 += svatt[ab + 3] * tanh_fast(bfh(pv.y) + scr[1024 + ab + 3]);
                acc0 += svatt[ab + 4] * tanh_fast(bfl(pv.z) + scr[1024 + ab + 4]);
                acc1 += svatt[ab + 5] * tanh_fast(bfh(pv.z) + scr[1024 + ab + 5]);
                acc0 += svatt[ab + 6] * tanh_fast(bfl(pv.w) + scr[1024 + ab + 6]);
                acc1 += svatt[ab + 7] * tanh_fast(bfh(pv.w) + scr[1024 + ab + 7]);
            }
            scr[1280 + tid] = acc0 + acc1;
        }
        __syncthreads();
        if (tid < 256)
            pe_buf[((size_t)t * 64 + b) * 1024 + q * 256 + tid] =
                scr[1280 + tid] + scr[1536 + tid];
        flag_bar(carr, crel, q, 4, (uint)(t * 4 + 2));

        // ---- P4: softmax (redundant per cluster block) + ctx GEMV e-slice ----
        {
            int s2 = tid & 255;
            const float* peb = pe_buf + ((size_t)t * 64 + b) * 1024;
            float e = peb[s2] + peb[256 + s2] + peb[512 + s2] + peb[768 + s2];
            float mk = smask[s2];
            e = e * (1.0f - mk) + mk * (-1e6f);
            float mx = e;
#pragma unroll
            for (int off = 1; off < 64; off <<= 1) mx = fmaxf(mx, __shfl_xor(mx, off));
            if (lane == 0) scr[3072 + wid] = mx;
            __syncthreads();
            mx = scr[3072];
#pragma unroll
            for (int w2 = 1; w2 < 8; ++w2) mx = fmaxf(mx, scr[3072 + w2]);
            float ex = __expf(e - mx);
            float sm = ex;
#pragma unroll
            for (int off = 1; off < 64; off <<= 1) sm += __shfl_xor(sm, off);
            if (lane == 0) scr[3080 + wid] = sm;
            __syncthreads();
            sm = scr[3080] + scr[3081] + scr[3082] + scr[3083];
            scr[1792 + s2] = ex / sm;
        }
        __syncthreads();
        // spread cout store over the cluster (64 scores each)
        if (tid < 64)
            cout[((size_t)t * 64 + b) * 256 + q * 64 + tid] = scr[1792 + q * 64 + tid];
        {
            // ctx GEMV: e-pair per thread (b32 LDS reads), 8 s-chunks of 32
            int e2 = tid & 63, sq = tid >> 6;
            float acc0 = 0.f, acc1 = 0.f;
#pragma unroll 8
            for (int i = 0; i < 32; ++i) {
                int ss = sq * 32 + i;
                uint cv = *(const uint*)&ctxT[ss * 128 + e2 * 2];
                float sc = scr[1792 + ss];
                acc0 = fmaf(sc, bfl(cv), acc0);
                acc1 = fmaf(sc, bfh(cv), acc1);
            }
            scr[2048 + sq * 128 + e2 * 2 + 0] = acc0;
            scr[2048 + sq * 128 + e2 * 2 + 1] = acc1;
        }
        __syncthreads();
        if (tid < 128) {
            float val = 0.f;
#pragma unroll
            for (int s8 = 0; s8 < 8; ++s8) val += scr[2048 + s8 * 128 + tid];
            int e = q * 128 + tid;
            ctx_hist[(size_t)t * 32768 + (size_t)b * 512 + e] = val;
            cswz[(size_t)t * 32768 + (size_t)b * 512 +
                 (((e >> 3) ^ (b >> 3)) << 3) + (e & 7)] = f2bf(val);
        }
        flag_bar(garr, grel, u, 32, (uint)(t * 4 + 3));
    }
}

// ---------------- batched copy gate ----------------
__global__ __launch_bounds__(256) void k_copy(
    const float* __restrict__ h_hist, const float* __restrict__ ctx_hist,
    const float* __restrict__ W_copy, const float* __restrict__ b_copy,
    float* __restrict__ out)
{
    const int tid = threadIdx.x;
    const int lane = tid & 63;
    const int tb = blockIdx.x * 4 + (tid >> 6);
    const float* hp = h_hist + (size_t)tb * DD;
    const float* cp = ctx_hist + (size_t)tb * DD;
    float acc = 0.f;
#pragma unroll
    for (int jj = 0; jj < 8; ++jj) {
        int k = lane + 64 * jj;
        acc = fmaf(hp[k], W_copy[k], acc);
        acc = fmaf(cp[k], W_copy[512 + k], acc);
    }
#pragma unroll
    for (int off = 1; off < 64; off <<= 1) acc += __shfl_xor(acc, off);
    if (lane == 0) out[tb] = sigmf(acc + b_copy[0]);
}

// ---------------- tail outputs ----------------
__global__ void k_final(const float* __restrict__ h_hist,
                        const float* __restrict__ ctx_hist,
                        float* __restrict__ dout)
{
    int idx = blockIdx.x * 256 + threadIdx.x;
    if (idx < 32768) {
        dout[1050624 + idx] = h_hist[31 * 32768 + idx];
    } else if (idx < 49152) {
        int i2 = idx - 32768;
        dout[1083392 + i2] = dout[524288 + 507904 + i2];
    } else {
        int i2 = idx - 49152;
        dout[1099776 + i2] = ctx_hist[31 * 32768 + i2];
    }
}

extern "C" void kernel_launch(void* const* d_in, const int* in_sizes, int n_in,
                              void* d_out, int out_size, void* d_ws, size_t ws_size,
                              hipStream_t stream)
{
    (void)in_sizes; (void)n_in; (void)out_size; (void)ws_size;
    const int*   ids      = (const int*)d_in[0];
    const float* hidden   = (const float*)d_in[1];
    const float* context  = (const float*)d_in[2];
    const float* mask     = (const float*)d_in[3];
    const float* init_att = (const float*)d_in[4];
    const float* emb_t    = (const float*)d_in[5];
    const float* W_ih     = (const float*)d_in[6];
    const float* W_hh     = (const float*)d_in[7];
    const float* b_ih     = (const float*)d_in[8];
    const float* b_hh     = (const float*)d_in[9];
    const float* W_pre    = (const float*)d_in[10];
    const float* b_pre    = (const float*)d_in[11];
    const float* W_q      = (const float*)d_in[12];
    const float* v_att    = (const float*)d_in[13];
    const float* W_copy   = (const float*)d_in[14];
    const float* b_copy   = (const float*)d_in[15];
    const float* W_read   = (const float*)d_in[16];
    const float* b_read   = (const float*)d_in[17];
    float* out = (float*)d_out;
    float* ws = (float*)d_ws;

    ushort* preb    = (ushort*)ws;
    float* gxe      = ws + 4194304;
    float* h_hist   = ws + 7340032;
    float* ctx_hist = ws + 8388608;
    float* pe_buf   = ws + 9437184;
    uint* Wpk       = (uint*)(ws + 11534336);
    uint* WqT       = (uint*)(ws + 12320768);
    ushort* hswz    = (ushort*)(ws + 12451840);
    ushort* cswz    = (ushort*)(ws + 12976128);
    uint* cnt       = (uint*)(ws + 13500416);
    float* cout     = out + 524288;

    hipMemsetAsync(cnt, 0, 16384, stream);
    mgemm<0><<<dim3(256, 8), 256, 0, stream>>>(context, nullptr, nullptr, nullptr,
                                               W_pre, b_pre, (void*)preb, 512, 512);
    mgemm<1><<<dim3(32, 24), 256, 0, stream>>>(emb_t, nullptr, nullptr, ids,
                                               W_ih, b_ih, (void*)gxe, 1024, 512);
    wprep2<<<1792, 512, 0, stream>>>(W_ih, W_hh, W_q, Wpk, WqT);
    {
        void* args[] = {
            (void*)&gxe, (void*)&hidden, (void*)&init_att, (void*)&context,
            (void*)&mask, (void*)&v_att, (void*)&b_hh, (void*)&preb,
            (void*)&Wpk, (void*)&WqT,
            (void*)&h_hist, (void*)&ctx_hist, (void*)&hswz, (void*)&cswz,
            (void*)&pe_buf, (void*)&cnt, (void*)&cout
        };
        hipLaunchCooperativeKernel((void*)k_steps, dim3(256), dim3(512), args, 0,
                                   stream);
    }
    mgemm<2><<<dim3(32, 8), 256, 0, stream>>>(emb_t, h_hist, ctx_hist, ids,
                                              W_read, b_read, (void*)out, 1536, 1536);
    k_copy<<<512, 256, 0, stream>>>(h_hist, ctx_hist, W_copy, b_copy, out + 1048576);
    k_final<<<320, 256, 0, stream>>>(h_hist, ctx_hist, out);
}

// Round 11
// 666.125 us; speedup vs baseline: 1.0287x; 1.0287x over previous
//
#include <hip/hip_runtime.h>
#include <hip/hip_bf16.h>

// Decoder: T=32, B=64, S=256, DEC=ENC=ATT=WV=512, V=32000, POOL=2
// Round 11: k_steps reverted to R8 (best: 520us) + two on-path micro-fixes
// (P3 dual accumulators; cout store spread over cluster; softmax scratch at
// 3072 fixing R8's latent alias). R9's hswz/cswz buffers dropped (off-path
// "optimization" that added pre-barrier store drains: 520->577 regression).
// mgemm gains an MT (m-tiles) template param: MODE 0 (pre) runs BM=128.
//
// ws layout (float units):
//   preb     ushort[64][256][512] @ 0         (4194304 f)
//   gxe      f32  [2048][1536]    @ 4194304   (3145728)
//   h_hist   f32  [32][64][512]   @ 7340032   (1048576)
//   ctx_hist f32  [32][64][512]   @ 8388608   (1048576)
//   pe_buf   f32  [32][64][4][256]@ 9437184   (2097152)
//   Wpk      uint [786432]        @ 11534336  (786432)
//   WqT      uint [256][512]      @ 12320768  (131072)
//   counters uint [4096]          @ 12451840  (4096)

typedef unsigned int uint;
typedef unsigned short ushort;
typedef __attribute__((ext_vector_type(8))) short s8v;   // 8 bf16
typedef __attribute__((ext_vector_type(4))) float f4v;   // 4 f32

#define DD 512

__device__ __forceinline__ float sigmf(float x) { return 1.0f / (1.0f + __expf(-x)); }
__device__ __forceinline__ float tanh_fast(float x) {
    float e = __expf(2.0f * x);
    return 1.0f - 2.0f / (e + 1.0f);
}
__device__ __forceinline__ ushort f2bf(float f) {
    uint b = __float_as_uint(f);
    return (ushort)((b + 0x7FFFu + ((b >> 16) & 1u)) >> 16);
}
__device__ __forceinline__ uint pk2(float a, float b) {
    return (uint)f2bf(a) | ((uint)f2bf(b) << 16);
}
__device__ __forceinline__ float bfl(uint u) { return __uint_as_float(u << 16); }
__device__ __forceinline__ float bfh(uint u) { return __uint_as_float(u & 0xFFFF0000u); }
__device__ __forceinline__ f4v MFMA(s8v a, s8v b, f4v c) {
    return __builtin_amdgcn_mfma_f32_16x16x32_bf16(a, b, c, 0, 0, 0);
}

// Flag-slot barrier (relaxed, no cache maintenance; see R7/R8 rationale).
__device__ __forceinline__ void flag_bar(uint* arr, uint* rel, int member,
                                         int nmem, uint tag) {
    __syncthreads();
    const int tid = threadIdx.x;
    if (tid == 0) {
        asm volatile("s_waitcnt vmcnt(0) lgkmcnt(0)" ::: "memory");
        __hip_atomic_store(arr + member, tag, __ATOMIC_RELAXED,
                           __HIP_MEMORY_SCOPE_AGENT);
    }
    if (member == 0) {
        if (tid > 0 && tid < nmem) {
            while (__hip_atomic_load(arr + tid, __ATOMIC_RELAXED,
                                     __HIP_MEMORY_SCOPE_AGENT) < tag) {}
        }
        if (tid == 0)
            __hip_atomic_store(rel, tag, __ATOMIC_RELAXED,
                               __HIP_MEMORY_SCOPE_AGENT);
    } else {
        if (tid == 0) {
            while (__hip_atomic_load(rel, __ATOMIC_RELAXED,
                                     __HIP_MEMORY_SCOPE_AGENT) < tag) {}
        }
    }
    __syncthreads();
}

// ================= unified MFMA GEMM: C[M,N] = A[M,K] @ B[N,K]^T + bias =======
// BM = MT*16 (MT=8 for MODE 0, 4 otherwise), BN = 64, 256 threads (4 waves).
template <int MODE, int MT>
__global__ __launch_bounds__(256) void mgemm(
    const float* __restrict__ A0, const float* __restrict__ A1,
    const float* __restrict__ A2, const int* __restrict__ ids,
    const float* __restrict__ Bm, const float* __restrict__ bias,
    void* __restrict__ Cout, int ldb, int K)
{
    __shared__ __align__(16) ushort Ab[MT * 16 * 32];
    __shared__ __align__(16) ushort Bb[64 * 32];
    __shared__ int rid[MT * 16];
    const int tid = threadIdx.x;
    const int m0 = blockIdx.x * (MT * 16), n0 = blockIdx.y * 64;
    if (MODE != 0 && tid < MT * 16) rid[tid] = ids[m0 + tid];
    const int lane = tid & 63;
    const int w = tid >> 6;
    const int sc = tid & 3;
    f4v acc[MT];
#pragma unroll
    for (int mt = 0; mt < MT; ++mt) acc[mt] = (f4v){0.f, 0.f, 0.f, 0.f};

    for (int k0 = 0; k0 < K; k0 += 32) {
        __syncthreads();
#pragma unroll
        for (int p = 0; p < MT / 4; ++p) {
            int row = p * 64 + (tid >> 2);
            const float* ap;
            int m = m0 + row;
            if (MODE == 0) {
                ap = A0 + (size_t)(m & 255) * 32768 + (size_t)(m >> 8) * 512 + k0 + sc * 8;
            } else if (MODE == 1) {
                ap = A0 + (size_t)rid[row] * 512 + k0 + sc * 8;
            } else {
                if (k0 < 512)       ap = A0 + (size_t)rid[row] * 512 + k0 + sc * 8;
                else if (k0 < 1024) ap = A1 + (size_t)m * 512 + (k0 - 512) + sc * 8;
                else                ap = A2 + (size_t)m * 512 + (k0 - 1024) + sc * 8;
            }
            float4 v0 = *(const float4*)ap;
            float4 v1 = *(const float4*)(ap + 4);
            uint4 pa;
            pa.x = pk2(v0.x, v0.y); pa.y = pk2(v0.z, v0.w);
            pa.z = pk2(v1.x, v1.y); pa.w = pk2(v1.z, v1.w);
            *(uint4*)&Ab[row * 32 + ((sc ^ (row & 3)) << 3)] = pa;
        }
        {
            int row = tid >> 2;
            const float* bp = Bm + (size_t)(n0 + row) * ldb + k0 + sc * 8;
            float4 w0 = *(const float4*)bp;
            float4 w1 = *(const float4*)(bp + 4);
            uint4 pb;
            pb.x = pk2(w0.x, w0.y); pb.y = pk2(w0.z, w0.w);
            pb.z = pk2(w1.x, w1.y); pb.w = pk2(w1.z, w1.w);
            *(uint4*)&Bb[row * 32 + ((sc ^ (row & 3)) << 3)] = pb;
        }
        __syncthreads();
        int rr = lane & 15, kc = lane >> 4;
        s8v bf = *(const s8v*)&Bb[(w * 16 + rr) * 32 + ((kc ^ (rr & 3)) << 3)];
#pragma unroll
        for (int mt = 0; mt < MT; ++mt) {
            s8v af = *(const s8v*)&Ab[(mt * 16 + rr) * 32 + ((kc ^ (rr & 3)) << 3)];
            acc[mt] = MFMA(af, bf, acc[mt]);
        }
    }
    float bv = bias[n0 + w * 16 + (lane & 15)];
#pragma unroll
    for (int mt = 0; mt < MT; ++mt) {
#pragma unroll
        for (int r2 = 0; r2 < 4; ++r2) {
            int m = m0 + mt * 16 + (lane >> 4) * 4 + r2;
            int n = n0 + w * 16 + (lane & 15);
            float v = acc[mt][r2] + bv;
            if (MODE == 0) {
                ((ushort*)Cout)[(size_t)m * 512 + n] = f2bf(v);
            } else if (MODE == 1) {
                ((float*)Cout)[(size_t)m * 1536 + n] = v;
            } else {
                float vm = fmaxf(v, __shfl_xor(v, 1));
                if (!(lane & 1)) ((float*)Cout)[(size_t)m * 256 + (n >> 1)] = vm;
            }
        }
    }
}

// ================= weight prep: Wpk (B-fragment order) + WqT ==================
__global__ __launch_bounds__(512) void wprep2(
    const float* __restrict__ W_ih, const float* __restrict__ W_hh,
    const float* __restrict__ W_q,
    uint* __restrict__ Wpk, uint* __restrict__ WqT)
{
    int id = blockIdx.x * 512 + threadIdx.x;
    if (id < 786432) {
        int l4 = id & 255;
        int chunk = id >> 8;
        int g = chunk % 3;
        int t2 = chunk / 3;
        int ks = t2 & 15;
        int mat = (t2 >> 4) & 1;
        int u = t2 >> 5;
        int lane = l4 >> 2, e2 = l4 & 3;
        int n = g * 512 + u * 16 + (lane & 15);
        int k = ks * 32 + ((lane >> 4) << 3) + e2 * 2;
        float w0, w1;
        if (mat == 0) {
            w0 = W_ih[(size_t)n * 1024 + 512 + k];
            w1 = W_ih[(size_t)n * 1024 + 512 + k + 1];
        } else {
            w0 = W_hh[(size_t)n * 512 + k];
            w1 = W_hh[(size_t)n * 512 + k + 1];
        }
        Wpk[id] = pk2(w0, w1);
    } else if (id < 917504) {
        int rid2 = id - 786432;
        int kp = rid2 >> 9, a = rid2 & 511;
        WqT[rid2] = pk2(W_q[(size_t)a * 512 + 2 * kp], W_q[(size_t)a * 512 + 2 * kp + 1]);
    }
}

// ================= persistent 32-step kernel (R8 structure) ===================
// 256 blocks x 512 thr (8 waves), 1/CU. q = blk>>6, b = blk&63, r = b&7,
// u = ((b>>3)<<2)|q. Group = 32 blocks same r (same XCD); cluster = 4 q's of b.
__global__ __launch_bounds__(512, 1) void k_steps(
    const float* __restrict__ gxe, const float* __restrict__ hidden,
    const float* __restrict__ init_att, const float* __restrict__ context,
    const float* __restrict__ mask, const float* __restrict__ v_att,
    const float* __restrict__ b_hh, const ushort* __restrict__ preb,
    const uint* __restrict__ Wpk, const uint* __restrict__ WqT,
    float* __restrict__ h_hist, float* __restrict__ ctx_hist,
    float* __restrict__ pe_buf, uint* __restrict__ cnt,
    float* __restrict__ cout)
{
    __shared__ __align__(16) ushort preT[256 * 128];   // 64KB [s][a-slice], swizzled
    __shared__ __align__(16) ushort ctxT[256 * 128];   // 64KB [s][e-slice], linear
    __shared__ __align__(16) float scr[6144];          // 24KB multiplexed
    __shared__ float smask[256];
    __shared__ float svatt[128];

    const int tid = threadIdx.x;
    const int blk = blockIdx.x;
    const int q = blk >> 6;
    const int b = blk & 63;
    const int r = b & 7;
    const int u = ((b >> 3) << 2) | q;
    const int lane = tid & 63;
    const int wid = __builtin_amdgcn_readfirstlane(tid >> 6);

    uint* garr = cnt + r * 64;
    uint* grel = cnt + 512 + r * 16;
    uint* carr = cnt + 1024 + b * 8;
    uint* crel = cnt + 2048 + b * 16;

    // ---- one-time staging: pre(bf16) + context(->bf16) into LDS ----
#pragma unroll
    for (int cc = 0; cc < 8; ++cc) {
        int cid = tid * 8 + cc;
        int s = cid >> 4, ch = cid & 15;
        int sw = (s ^ (s >> 3)) & 7;
        uint4 pv = *(const uint4*)(preb + ((size_t)(b * 256 + s)) * 512 + q * 128 + ch * 8);
        *(uint4*)&preT[s * 128 + ((ch ^ sw) << 3)] = pv;
        const float* cp = context + ((size_t)s * 64 + b) * 512 + q * 128 + ch * 8;
        float4 c0 = *(const float4*)cp;
        float4 c1 = *(const float4*)(cp + 4);
        uint4 cv;
        cv.x = pk2(c0.x, c0.y); cv.y = pk2(c0.z, c0.w);
        cv.z = pk2(c1.x, c1.y); cv.w = pk2(c1.z, c1.w);
        *(uint4*)&ctxT[s * 128 + ch * 8] = cv;
    }
    if (tid < 256) smask[tid] = mask[b * 256 + tid];
    else if (tid < 384) svatt[tid - 256] = v_att[q * 128 + (tid - 256)];

    // ---- register-resident weights (loop-invariant) ----
    const int mat_w = wid >> 2, kw = wid & 3;   // wave role in P1
    s8v wr0[4], wr1[4], wr2[4];
#pragma unroll
    for (int s = 0; s < 4; ++s) {
        int ks = kw * 4 + s;
        const uint* wb = Wpk + ((((u * 2 + mat_w) * 16 + ks) * 3) << 8) + (lane << 2);
        wr0[s] = *(const s8v*)(wb);
        wr1[s] = *(const s8v*)(wb + 256);
        wr2[s] = *(const s8v*)(wb + 512);
    }
    const int a_p2 = tid & 127, dq_p2 = tid >> 7;
    uint wqreg[64];
#pragma unroll
    for (int i = 0; i < 64; ++i)
        wqreg[i] = WqT[(size_t)(dq_p2 * 64 + i) * 512 + q * 128 + a_p2];

    const int bloc = tid >> 4, jj = tid & 15;
    int bb_c = 0, d_c = 0, eidx = 0;
    float bh0 = 0.f, bh1 = 0.f, bh2 = 0.f;
    if (tid < 128) {
        bb_c = r + bloc * 8;
        d_c = u * 16 + jj;
        eidx = ((jj + ((bloc >> 2) << 4)) << 2) + (bloc & 3);
        bh0 = b_hh[d_c]; bh1 = b_hh[512 + d_c]; bh2 = b_hh[1024 + d_c];
    }

    for (int t = 0; t < 32; ++t) {
        const float* ctxp = t ? (ctx_hist + (size_t)(t - 1) * 32768) : init_att;
        const float* hp = t ? (h_hist + (size_t)(t - 1) * 32768) : hidden;

        // ---- prefetch critical-path globals (overlap with P1a/P1b) ----
        float gx0 = 0.f, gx1 = 0.f, gx2 = 0.f, hpv = 0.f;
        if (tid < 128) {
            const float* gp = gxe + ((size_t)t * 64 + bb_c) * 1536 + d_c;
            gx0 = gp[0]; gx1 = gp[512]; gx2 = gp[1024];
            hpv = hp[(size_t)bb_c * 512 + d_c];
        }

        // ---- P1a: stage x (ctx_prev, h_prev for group's 8 b's) -> LDS bf16 ----
        __syncthreads();
        {
            int c2 = tid & 31, row = (tid >> 5) & 7, mat = tid >> 8;
            const float* src = mat ? hp : ctxp;
            int bb = r + row * 8;
            const float* sp = src + (size_t)bb * 512 + c2 * 16;
            float4 v0 = *(const float4*)sp, v1 = *(const float4*)(sp + 4);
            float4 v2 = *(const float4*)(sp + 8), v3 = *(const float4*)(sp + 12);
            uint4 p0, p1;
            p0.x = pk2(v0.x, v0.y); p0.y = pk2(v0.z, v0.w);
            p0.z = pk2(v1.x, v1.y); p0.w = pk2(v1.z, v1.w);
            p1.x = pk2(v2.x, v2.y); p1.y = pk2(v2.z, v2.w);
            p1.z = pk2(v3.x, v3.y); p1.w = pk2(v3.z, v3.w);
            char* xb = (char*)scr + mat * 8192 + row * 1024;
            int c0 = c2 * 2;
            *(uint4*)(xb + ((c0 ^ row) << 4)) = p0;
            *(uint4*)(xb + (((c0 + 1) ^ row) << 4)) = p1;
        }
        __syncthreads();
        // ---- P1b: MFMA with register weights ----
        f4v ac0 = (f4v){0.f, 0.f, 0.f, 0.f};
        f4v ac1 = ac0, ac2 = ac0;
        {
            const char* xbase = (const char*)scr + mat_w * 8192 + (lane & 15) * 1024;
            int rsw = (lane & 15) & 7;
#pragma unroll
            for (int s = 0; s < 4; ++s) {
                int ch = kw * 16 + s * 4 + (lane >> 4);
                s8v af = *(const s8v*)(xbase + ((ch ^ rsw) << 4));
                ac0 = MFMA(af, wr0[s], ac0);
                ac1 = MFMA(af, wr1[s], ac1);
                ac2 = MFMA(af, wr2[s], ac2);
            }
        }
        __syncthreads();   // all waves done reading x-stage; rb aliases it
        {
            f4v* rb = (f4v*)scr;
            rb[((mat_w * 3 + 0) * 4 + kw) * 64 + lane] = ac0;
            rb[((mat_w * 3 + 1) * 4 + kw) * 64 + lane] = ac1;
            rb[((mat_w * 3 + 2) * 4 + kw) * 64 + lane] = ac2;
        }
        __syncthreads();
        // ---- P1c: reduce + gates (128 threads: 8 b x 16 d) ----
        if (tid < 128) {
            float AX[3], AH[3];
#pragma unroll
            for (int g = 0; g < 3; ++g) {
                float sx = 0.f, sh = 0.f;
#pragma unroll
                for (int kw2 = 0; kw2 < 4; ++kw2) {
                    sx += scr[((0 + g) * 4 + kw2) * 256 + eidx];
                    sh += scr[((3 + g) * 4 + kw2) * 256 + eidx];
                }
                AX[g] = sx;
                AH[g] = sh;
            }
            AX[0] += gx0; AX[1] += gx1; AX[2] += gx2;
            AH[0] += bh0; AH[1] += bh1; AH[2] += bh2;
            float rr = sigmf(AX[0] + AH[0]);
            float zz = sigmf(AX[1] + AH[1]);
            float nn = tanh_fast(AX[2] + rr * AH[2]);
            h_hist[(size_t)t * 32768 + (size_t)bb_c * 512 + d_c] =
                (1.0f - zz) * nn + zz * hpv;
        }
        flag_bar(garr, grel, u, 32, (uint)(t * 4 + 1));

        // ---- P2: target a-slice q*128 from full h[b] (register Wq) ----
        scr[tid] = h_hist[(size_t)t * 32768 + (size_t)b * 512 + tid];
        __syncthreads();
        {
            float acc = 0.f;
#pragma unroll
            for (int i = 0; i < 64; ++i) {
                uint w = wqreg[i];
                acc = fmaf(bfl(w), scr[(dq_p2 * 64 + i) * 2 + 0],
                           fmaf(bfh(w), scr[(dq_p2 * 64 + i) * 2 + 1], acc));
            }
            scr[512 + tid] = acc;
        }
        __syncthreads();
        if (tid < 128)
            scr[1024 + tid] = scr[512 + tid] + scr[640 + tid] +
                              scr[768 + tid] + scr[896 + tid];
        __syncthreads();

        // ---- P3: partial energy over a-slice, all 256 s (dual accumulators) --
        {
            int s = tid & 255, hf = tid >> 8;
            int sw = (s ^ (s >> 3)) & 7;
            float acc0 = 0.f, acc1 = 0.f;
#pragma unroll
            for (int c8 = 0; c8 < 8; ++c8) {
                int ch = hf * 8 + c8;
                uint4 pv = *(const uint4*)&preT[s * 128 + ((ch ^ sw) << 3)];
                int ab = ch * 8;
                acc0 += svatt[ab + 0] * tanh_fast(bfl(pv.x) + scr[1024 + ab + 0]);
                acc1 += svatt[ab + 1] * tanh_fast(bfh(pv.x) + scr[1024 + ab + 1]);
                acc0 += svatt[ab + 2] * tanh_fast(bfl(pv.y) + scr[1024 + ab + 2]);
                acc1 += svatt[ab + 3] * tanh_fast(bfh(pv.y) + scr[1024 + ab + 3]);
                acc0 += svatt[ab + 4] * tanh_fast(bfl(pv.z) + scr[1024 + ab + 4]);
                acc1 += svatt[ab + 5] * tanh_fast(bfh(pv.z) + scr[1024 + ab + 5]);
                acc0 += svatt[ab + 6] * tanh_fast(bfl(pv.w) + scr[1024 + ab + 6]);
                acc1 += svatt[ab + 7] * tanh_fast(bfh(pv.w) + scr[1024 + ab + 7]);
            }
            scr[1280 + tid] = acc0 + acc1;
        }
        __syncthreads();
        if (tid < 256)
            pe_buf[((size_t)t * 64 + b) * 1024 + q * 256 + tid] =
                scr[1280 + tid] + scr[1536 + tid];
        flag_bar(carr, crel, q, 4, (uint)(t * 4 + 2));

        // ---- P4: softmax (redundant per cluster block) + ctx GEMV e-slice ----
        {
            int s2 = tid & 255;
            const float* peb = pe_buf + ((size_t)t * 64 + b) * 1024;
            float e = peb[s2] + peb[256 + s2] + peb[512 + s2] + peb[768 + s2];
            float mk = smask[s2];
            e = e * (1.0f - mk) + mk * (-1e6f);
            float mx = e;
#pragma unroll
            for (int off = 1; off < 64; off <<= 1) mx = fmaxf(mx, __shfl_xor(mx, off));
            if (lane == 0) scr[3072 + wid] = mx;
            __syncthreads();
            mx = scr[3072];
#pragma unroll
            for (int w2 = 1; w2 < 8; ++w2) mx = fmaxf(mx, scr[3072 + w2]);
            float ex = __expf(e - mx);
            float sm = ex;
#pragma unroll
            for (int off = 1; off < 64; off <<= 1) sm += __shfl_xor(sm, off);
            if (lane == 0) scr[3080 + wid] = sm;
            __syncthreads();
            sm = scr[3080] + scr[3081] + scr[3082] + scr[3083];
            scr[1792 + s2] = ex / sm;
        }
        __syncthreads();
        // spread cout store over the cluster (64 scores each) — kills q0 skew
        if (tid < 64)
            cout[((size_t)t * 64 + b) * 256 + q * 64 + tid] = scr[1792 + q * 64 + tid];
        {
            // ctx GEMV: e-pair per thread (b32 LDS reads), 8 s-chunks of 32
            int e2 = tid & 63, sq = tid >> 6;
            float acc0 = 0.f, acc1 = 0.f;
#pragma unroll 8
            for (int i = 0; i < 32; ++i) {
                int ss = sq * 32 + i;
                uint cv = *(const uint*)&ctxT[ss * 128 + e2 * 2];
                float sc = scr[1792 + ss];
                acc0 = fmaf(sc, bfl(cv), acc0);
                acc1 = fmaf(sc, bfh(cv), acc1);
            }
            scr[2048 + sq * 128 + e2 * 2 + 0] = acc0;
            scr[2048 + sq * 128 + e2 * 2 + 1] = acc1;
        }
        __syncthreads();
        if (tid < 128) {
            float val = 0.f;
#pragma unroll
            for (int s8 = 0; s8 < 8; ++s8) val += scr[2048 + s8 * 128 + tid];
            ctx_hist[(size_t)t * 32768 + (size_t)b * 512 + q * 128 + tid] = val;
        }
        flag_bar(garr, grel, u, 32, (uint)(t * 4 + 3));
    }
}

// ---------------- batched copy gate ----------------
__global__ __launch_bounds__(256) void k_copy(
    const float* __restrict__ h_hist, const float* __restrict__ ctx_hist,
    const float* __restrict__ W_copy, const float* __restrict__ b_copy,
    float* __restrict__ out)
{
    const int tid = threadIdx.x;
    const int lane = tid & 63;
    const int tb = blockIdx.x * 4 + (tid >> 6);
    const float* hp = h_hist + (size_t)tb * DD;
    const float* cp = ctx_hist + (size_t)tb * DD;
    float acc = 0.f;
#pragma unroll
    for (int jj = 0; jj < 8; ++jj) {
        int k = lane + 64 * jj;
        acc = fmaf(hp[k], W_copy[k], acc);
        acc = fmaf(cp[k], W_copy[512 + k], acc);
    }
#pragma unroll
    for (int off = 1; off < 64; off <<= 1) acc += __shfl_xor(acc, off);
    if (lane == 0) out[tb] = sigmf(acc + b_copy[0]);
}

// ---------------- tail outputs ----------------
__global__ void k_final(const float* __restrict__ h_hist,
                        const float* __restrict__ ctx_hist,
                        float* __restrict__ dout)
{
    int idx = blockIdx.x * 256 + threadIdx.x;
    if (idx < 32768) {
        dout[1050624 + idx] = h_hist[31 * 32768 + idx];
    } else if (idx < 49152) {
        int i2 = idx - 32768;
        dout[1083392 + i2] = dout[524288 + 507904 + i2];
    } else {
        int i2 = idx - 49152;
        dout[1099776 + i2] = ctx_hist[31 * 32768 + i2];
    }
}

extern "C" void kernel_launch(void* const* d_in, const int* in_sizes, int n_in,
                              void* d_out, int out_size, void* d_ws, size_t ws_size,
                              hipStream_t stream)
{
    (void)in_sizes; (void)n_in; (void)out_size; (void)ws_size;
    const int*   ids      = (const int*)d_in[0];
    const float* hidden   = (const float*)d_in[1];
    const float* context  = (const float*)d_in[2];
    const float* mask     = (const float*)d_in[3];
    const float* init_att = (const float*)d_in[4];
    const float* emb_t    = (const float*)d_in[5];
    const float* W_ih     = (const float*)d_in[6];
    const float* W_hh     = (const float*)d_in[7];
    const float* b_ih     = (const float*)d_in[8];
    const float* b_hh     = (const float*)d_in[9];
    const float* W_pre    = (const float*)d_in[10];
    const float* b_pre    = (const float*)d_in[11];
    const float* W_q      = (const float*)d_in[12];
    const float* v_att    = (const float*)d_in[13];
    const float* W_copy   = (const float*)d_in[14];
    const float* b_copy   = (const float*)d_in[15];
    const float* W_read   = (const float*)d_in[16];
    const float* b_read   = (const float*)d_in[17];
    float* out = (float*)d_out;
    float* ws = (float*)d_ws;

    ushort* preb    = (ushort*)ws;
    float* gxe      = ws + 4194304;
    float* h_hist   = ws + 7340032;
    float* ctx_hist = ws + 8388608;
    float* pe_buf   = ws + 9437184;
    uint* Wpk       = (uint*)(ws + 11534336);
    uint* WqT       = (uint*)(ws + 12320768);
    uint* cnt       = (uint*)(ws + 12451840);
    float* cout     = out + 524288;

    hipMemsetAsync(cnt, 0, 16384, stream);
    // pre = ctx_t @ W_pre^T + b_pre  (bf16 out), BM=128
    mgemm<0, 8><<<dim3(128, 8), 256, 0, stream>>>(context, nullptr, nullptr, nullptr,
                                                  W_pre, b_pre, (void*)preb, 512, 512);
    // gxe = emb @ W_ih[:, :512]^T + b_ih  (f32 out, ldc 1536)
    mgemm<1, 4><<<dim3(32, 24), 256, 0, stream>>>(emb_t, nullptr, nullptr, ids,
                                                  W_ih, b_ih, (void*)gxe, 1024, 512);
    wprep2<<<1792, 512, 0, stream>>>(W_ih, W_hh, W_q, Wpk, WqT);
    {
        void* args[] = {
            (void*)&gxe, (void*)&hidden, (void*)&init_att, (void*)&context,
            (void*)&mask, (void*)&v_att, (void*)&b_hh, (void*)&preb,
            (void*)&Wpk, (void*)&WqT,
            (void*)&h_hist, (void*)&ctx_hist, (void*)&pe_buf, (void*)&cnt,
            (void*)&cout
        };
        hipLaunchCooperativeKernel((void*)k_steps, dim3(256), dim3(512), args, 0,
                                   stream);
    }
    mgemm<2, 4><<<dim3(32, 8), 256, 0, stream>>>(emb_t, h_hist, ctx_hist, ids,
                                                 W_read, b_read, (void*)out, 1536, 1536);
    k_copy<<<512, 256, 0, stream>>>(h_hist, ctx_hist, W_copy, b_copy, out + 1048576);
    k_final<<<320, 256, 0, stream>>>(h_hist, ctx_hist, out);
}

// Round 12
// 555.437 us; speedup vs baseline: 1.2337x; 1.1993x over previous
//
#include <hip/hip_runtime.h>
#include <hip/hip_bf16.h>

// Decoder: T=32, B=64, S=256, DEC=ENC=ATT=WV=512, V=32000, POOL=2
// Round 12: R8 k_steps body + split-phase final barrier (arrive early; during
// the wait: prefetch next gxe/h_prev and stage next step's h-half of the
// x-tile, which is already globally visible; post-wait stage only ctx-half).
// All prep kernels fused into k_prep (incl. cnt zeroing), all tail kernels
// into k_post: 8 graph nodes -> 3.
//
// ws layout (float units):
//   preb     ushort[64][256][512] @ 0         (4194304 f)
//   gxe      f32  [2048][1536]    @ 4194304   (3145728)
//   h_hist   f32  [32][64][512]   @ 7340032   (1048576)
//   ctx_hist f32  [32][64][512]   @ 8388608   (1048576)
//   pe_buf   f32  [32][64][4][256]@ 9437184   (2097152)
//   Wpk      uint [786432]        @ 11534336  (786432)
//   WqT      uint [256][512]      @ 12320768  (131072)
//   counters uint [4096]          @ 12451840  (4096)

typedef unsigned int uint;
typedef unsigned short ushort;
typedef __attribute__((ext_vector_type(8))) short s8v;   // 8 bf16
typedef __attribute__((ext_vector_type(4))) float f4v;   // 4 f32

#define DD 512

__device__ __forceinline__ float sigmf(float x) { return 1.0f / (1.0f + __expf(-x)); }
__device__ __forceinline__ float tanh_fast(float x) {
    float e = __expf(2.0f * x);
    return 1.0f - 2.0f / (e + 1.0f);
}
__device__ __forceinline__ ushort f2bf(float f) {
    uint b = __float_as_uint(f);
    return (ushort)((b + 0x7FFFu + ((b >> 16) & 1u)) >> 16);
}
__device__ __forceinline__ uint pk2(float a, float b) {
    return (uint)f2bf(a) | ((uint)f2bf(b) << 16);
}
__device__ __forceinline__ float bfl(uint u) { return __uint_as_float(u << 16); }
__device__ __forceinline__ float bfh(uint u) { return __uint_as_float(u & 0xFFFF0000u); }
__device__ __forceinline__ f4v MFMA(s8v a, s8v b, f4v c) {
    return __builtin_amdgcn_mfma_f32_16x16x32_bf16(a, b, c, 0, 0, 0);
}

// Flag-slot barrier (relaxed, no cache maintenance; R7/R8 rationale).
__device__ __forceinline__ void flag_bar(uint* arr, uint* rel, int member,
                                         int nmem, uint tag) {
    __syncthreads();
    const int tid = threadIdx.x;
    if (tid == 0) {
        asm volatile("s_waitcnt vmcnt(0) lgkmcnt(0)" ::: "memory");
        __hip_atomic_store(arr + member, tag, __ATOMIC_RELAXED,
                           __HIP_MEMORY_SCOPE_AGENT);
    }
    if (member == 0) {
        if (tid > 0 && tid < nmem) {
            while (__hip_atomic_load(arr + tid, __ATOMIC_RELAXED,
                                     __HIP_MEMORY_SCOPE_AGENT) < tag) {}
        }
        if (tid == 0)
            __hip_atomic_store(rel, tag, __ATOMIC_RELAXED,
                               __HIP_MEMORY_SCOPE_AGENT);
    } else {
        if (tid == 0) {
            while (__hip_atomic_load(rel, __ATOMIC_RELAXED,
                                     __HIP_MEMORY_SCOPE_AGENT) < tag) {}
        }
    }
    __syncthreads();
}

// ================= MFMA GEMM body: C[M,N] = A[M,K] @ B[N,K]^T + bias =========
// BM = MT*16, BN = 64, 256 threads (4 waves).
template <int MODE, int MT>
__device__ __forceinline__ void mgemm_body(
    const float* __restrict__ A0, const float* __restrict__ A1,
    const float* __restrict__ A2, const int* __restrict__ ids,
    const float* __restrict__ Bm, const float* __restrict__ bias,
    void* __restrict__ Cout, int ldb, int K, int bx, int by,
    ushort* Ab, ushort* Bb, int* rid)
{
    const int tid = threadIdx.x;
    const int m0 = bx * (MT * 16), n0 = by * 64;
    if (MODE != 0 && tid < MT * 16) rid[tid] = ids[m0 + tid];
    const int lane = tid & 63;
    const int w = tid >> 6;
    const int sc = tid & 3;
    f4v acc[MT];
#pragma unroll
    for (int mt = 0; mt < MT; ++mt) acc[mt] = (f4v){0.f, 0.f, 0.f, 0.f};

    for (int k0 = 0; k0 < K; k0 += 32) {
        __syncthreads();
#pragma unroll
        for (int p = 0; p < MT / 4; ++p) {
            int row = p * 64 + (tid >> 2);
            const float* ap;
            int m = m0 + row;
            if (MODE == 0) {
                ap = A0 + (size_t)(m & 255) * 32768 + (size_t)(m >> 8) * 512 + k0 + sc * 8;
            } else if (MODE == 1) {
                ap = A0 + (size_t)rid[row] * 512 + k0 + sc * 8;
            } else {
                if (k0 < 512)       ap = A0 + (size_t)rid[row] * 512 + k0 + sc * 8;
                else if (k0 < 1024) ap = A1 + (size_t)m * 512 + (k0 - 512) + sc * 8;
                else                ap = A2 + (size_t)m * 512 + (k0 - 1024) + sc * 8;
            }
            float4 v0 = *(const float4*)ap;
            float4 v1 = *(const float4*)(ap + 4);
            uint4 pa;
            pa.x = pk2(v0.x, v0.y); pa.y = pk2(v0.z, v0.w);
            pa.z = pk2(v1.x, v1.y); pa.w = pk2(v1.z, v1.w);
            *(uint4*)&Ab[row * 32 + ((sc ^ (row & 3)) << 3)] = pa;
        }
        {
            int row = tid >> 2;
            const float* bp = Bm + (size_t)(n0 + row) * ldb + k0 + sc * 8;
            float4 w0 = *(const float4*)bp;
            float4 w1 = *(const float4*)(bp + 4);
            uint4 pb;
            pb.x = pk2(w0.x, w0.y); pb.y = pk2(w0.z, w0.w);
            pb.z = pk2(w1.x, w1.y); pb.w = pk2(w1.z, w1.w);
            *(uint4*)&Bb[row * 32 + ((sc ^ (row & 3)) << 3)] = pb;
        }
        __syncthreads();
        int rr = lane & 15, kc = lane >> 4;
        s8v bf = *(const s8v*)&Bb[(w * 16 + rr) * 32 + ((kc ^ (rr & 3)) << 3)];
#pragma unroll
        for (int mt = 0; mt < MT; ++mt) {
            s8v af = *(const s8v*)&Ab[(mt * 16 + rr) * 32 + ((kc ^ (rr & 3)) << 3)];
            acc[mt] = MFMA(af, bf, acc[mt]);
        }
    }
    float bv = bias[n0 + w * 16 + (lane & 15)];
#pragma unroll
    for (int mt = 0; mt < MT; ++mt) {
#pragma unroll
        for (int r2 = 0; r2 < 4; ++r2) {
            int m = m0 + mt * 16 + (lane >> 4) * 4 + r2;
            int n = n0 + w * 16 + (lane & 15);
            float v = acc[mt][r2] + bv;
            if (MODE == 0) {
                ((ushort*)Cout)[(size_t)m * 512 + n] = f2bf(v);
            } else if (MODE == 1) {
                ((float*)Cout)[(size_t)m * 1536 + n] = v;
            } else {
                float vm = fmaxf(v, __shfl_xor(v, 1));
                if (!(lane & 1)) ((float*)Cout)[(size_t)m * 256 + (n >> 1)] = vm;
            }
        }
    }
}

// ================= fused prep: pre-GEMM | gxe-GEMM | weight pack | cnt zero ===
__global__ __launch_bounds__(256) void k_prep(
    const float* __restrict__ context, const float* __restrict__ emb_t,
    const int* __restrict__ ids,
    const float* __restrict__ W_ih, const float* __restrict__ W_hh,
    const float* __restrict__ W_q, const float* __restrict__ W_pre,
    const float* __restrict__ b_pre, const float* __restrict__ b_ih,
    ushort* __restrict__ preb, float* __restrict__ gxe,
    uint* __restrict__ Wpk, uint* __restrict__ WqT, uint* __restrict__ cnt)
{
    __shared__ __align__(16) ushort Ab[8 * 16 * 32];
    __shared__ __align__(16) ushort Bb[64 * 32];
    __shared__ int rid[128];
    const int bid = blockIdx.x;
    if (bid < 1024) {
        mgemm_body<0, 8>(context, nullptr, nullptr, nullptr, W_pre, b_pre,
                         (void*)preb, 512, 512, bid & 127, bid >> 7, Ab, Bb, rid);
    } else if (bid < 1792) {
        int b2 = bid - 1024;
        mgemm_body<1, 4>(emb_t, nullptr, nullptr, ids, W_ih, b_ih,
                         (void*)gxe, 1024, 512, b2 & 31, b2 >> 5, Ab, Bb, rid);
    } else if (bid < 5376) {
        int id = (bid - 1792) * 256 + threadIdx.x;
        if (id < 786432) {
            int l4 = id & 255;
            int chunk = id >> 8;
            int g = chunk % 3;
            int t2 = chunk / 3;
            int ks = t2 & 15;
            int mat = (t2 >> 4) & 1;
            int u = t2 >> 5;
            int lane = l4 >> 2, e2 = l4 & 3;
            int n = g * 512 + u * 16 + (lane & 15);
            int k = ks * 32 + ((lane >> 4) << 3) + e2 * 2;
            float w0, w1;
            if (mat == 0) {
                w0 = W_ih[(size_t)n * 1024 + 512 + k];
                w1 = W_ih[(size_t)n * 1024 + 512 + k + 1];
            } else {
                w0 = W_hh[(size_t)n * 512 + k];
                w1 = W_hh[(size_t)n * 512 + k + 1];
            }
            Wpk[id] = pk2(w0, w1);
        } else {
            int rid2 = id - 786432;
            int kp = rid2 >> 9, a = rid2 & 511;
            WqT[rid2] = pk2(W_q[(size_t)a * 512 + 2 * kp],
                            W_q[(size_t)a * 512 + 2 * kp + 1]);
        }
    } else {
        int t4 = threadIdx.x * 16;
#pragma unroll
        for (int i = 0; i < 16; ++i) cnt[t4 + i] = 0;
    }
}

// ================= persistent 32-step kernel (R8 body, split final barrier) ===
// 256 blocks x 512 thr (8 waves), 1/CU. q = blk>>6, b = blk&63, r = b&7,
// u = ((b>>3)<<2)|q. Group = 32 blocks same r (same XCD); cluster = 4 q's of b.
__global__ __launch_bounds__(512, 1) void k_steps(
    const float* __restrict__ gxe, const float* __restrict__ hidden,
    const float* __restrict__ init_att, const float* __restrict__ context,
    const float* __restrict__ mask, const float* __restrict__ v_att,
    const float* __restrict__ b_hh, const ushort* __restrict__ preb,
    const uint* __restrict__ Wpk, const uint* __restrict__ WqT,
    float* __restrict__ h_hist, float* __restrict__ ctx_hist,
    float* __restrict__ pe_buf, uint* __restrict__ cnt,
    float* __restrict__ cout)
{
    __shared__ __align__(16) ushort preT[256 * 128];   // 64KB [s][a-slice], swizzled
    __shared__ __align__(16) ushort ctxT[256 * 128];   // 64KB [s][e-slice], linear
    __shared__ __align__(16) float scr[6144];          // 24KB multiplexed
    __shared__ float smask[256];
    __shared__ float svatt[128];

    const int tid = threadIdx.x;
    const int blk = blockIdx.x;
    const int q = blk >> 6;
    const int b = blk & 63;
    const int r = b & 7;
    const int u = ((b >> 3) << 2) | q;
    const int lane = tid & 63;
    const int wid = __builtin_amdgcn_readfirstlane(tid >> 6);

    uint* garr = cnt + r * 64;
    uint* grel = cnt + 512 + r * 16;
    uint* carr = cnt + 1024 + b * 8;
    uint* crel = cnt + 2048 + b * 16;

    // ---- one-time staging: pre(bf16) + context(->bf16) into LDS ----
#pragma unroll
    for (int cc = 0; cc < 8; ++cc) {
        int cid = tid * 8 + cc;
        int s = cid >> 4, ch = cid & 15;
        int sw = (s ^ (s >> 3)) & 7;
        uint4 pv = *(const uint4*)(preb + ((size_t)(b * 256 + s)) * 512 + q * 128 + ch * 8);
        *(uint4*)&preT[s * 128 + ((ch ^ sw) << 3)] = pv;
        const float* cp = context + ((size_t)s * 64 + b) * 512 + q * 128 + ch * 8;
        float4 c0 = *(const float4*)cp;
        float4 c1 = *(const float4*)(cp + 4);
        uint4 cv;
        cv.x = pk2(c0.x, c0.y); cv.y = pk2(c0.z, c0.w);
        cv.z = pk2(c1.x, c1.y); cv.w = pk2(c1.z, c1.w);
        *(uint4*)&ctxT[s * 128 + ch * 8] = cv;
    }
    if (tid < 256) smask[tid] = mask[b * 256 + tid];
    else if (tid < 384) svatt[tid - 256] = v_att[q * 128 + (tid - 256)];

    // ---- register-resident weights (loop-invariant) ----
    const int mat_w = wid >> 2, kw = wid & 3;   // wave role in P1
    s8v wr0[4], wr1[4], wr2[4];
#pragma unroll
    for (int s = 0; s < 4; ++s) {
        int ks = kw * 4 + s;
        const uint* wb = Wpk + ((((u * 2 + mat_w) * 16 + ks) * 3) << 8) + (lane << 2);
        wr0[s] = *(const s8v*)(wb);
        wr1[s] = *(const s8v*)(wb + 256);
        wr2[s] = *(const s8v*)(wb + 512);
    }
    const int a_p2 = tid & 127, dq_p2 = tid >> 7;
    uint wqreg[64];
#pragma unroll
    for (int i = 0; i < 64; ++i)
        wqreg[i] = WqT[(size_t)(dq_p2 * 64 + i) * 512 + q * 128 + a_p2];

    const int bloc = tid >> 4, jj = tid & 15;
    int bb_c = 0, d_c = 0, eidx = 0;
    float bh0 = 0.f, bh1 = 0.f, bh2 = 0.f;
    if (tid < 128) {
        bb_c = r + bloc * 8;
        d_c = u * 16 + jj;
        eidx = ((jj + ((bloc >> 2) << 4)) << 2) + (bloc & 3);
        bh0 = b_hh[d_c]; bh1 = b_hh[512 + d_c]; bh2 = b_hh[1024 + d_c];
    }

    // ---- t=0 prefetch + x-stage (ctx=init_att, h=hidden) ----
    float gx0 = 0.f, gx1 = 0.f, gx2 = 0.f, hpv = 0.f;
    if (tid < 128) {
        const float* gp = gxe + (size_t)bb_c * 1536 + d_c;
        gx0 = gp[0]; gx1 = gp[512]; gx2 = gp[1024];
        hpv = hidden[(size_t)bb_c * 512 + d_c];
    }
    {
        int c = tid & 63, row = tid >> 6;
        int bb = r + row * 8;
        const float* sp0 = init_att + (size_t)bb * 512 + c * 8;
        float4 a0 = *(const float4*)sp0, a1 = *(const float4*)(sp0 + 4);
        uint4 p0;
        p0.x = pk2(a0.x, a0.y); p0.y = pk2(a0.z, a0.w);
        p0.z = pk2(a1.x, a1.y); p0.w = pk2(a1.z, a1.w);
        *(uint4*)((char*)scr + row * 1024 + ((c ^ row) << 4)) = p0;
        const float* sp1 = hidden + (size_t)bb * 512 + c * 8;
        float4 b0 = *(const float4*)sp1, b1 = *(const float4*)(sp1 + 4);
        uint4 p1;
        p1.x = pk2(b0.x, b0.y); p1.y = pk2(b0.z, b0.w);
        p1.z = pk2(b1.x, b1.y); p1.w = pk2(b1.z, b1.w);
        *(uint4*)((char*)scr + 8192 + row * 1024 + ((c ^ row) << 4)) = p1;
    }
    __syncthreads();

    for (int t = 0; t < 32; ++t) {
        // ---- P1b: MFMA with register weights (x staged at end of prev step) --
        f4v ac0 = (f4v){0.f, 0.f, 0.f, 0.f};
        f4v ac1 = ac0, ac2 = ac0;
        {
            const char* xbase = (const char*)scr + mat_w * 8192 + (lane & 15) * 1024;
            int rsw = (lane & 15) & 7;
#pragma unroll
            for (int s = 0; s < 4; ++s) {
                int ch = kw * 16 + s * 4 + (lane >> 4);
                s8v af = *(const s8v*)(xbase + ((ch ^ rsw) << 4));
                ac0 = MFMA(af, wr0[s], ac0);
                ac1 = MFMA(af, wr1[s], ac1);
                ac2 = MFMA(af, wr2[s], ac2);
            }
        }
        __syncthreads();   // all waves done reading x-stage; rb aliases it
        {
            f4v* rb = (f4v*)scr;
            rb[((mat_w * 3 + 0) * 4 + kw) * 64 + lane] = ac0;
            rb[((mat_w * 3 + 1) * 4 + kw) * 64 + lane] = ac1;
            rb[((mat_w * 3 + 2) * 4 + kw) * 64 + lane] = ac2;
        }
        __syncthreads();
        // ---- P1c: reduce + gates (128 threads: 8 b x 16 d) ----
        if (tid < 128) {
            float AX[3], AH[3];
#pragma unroll
            for (int g = 0; g < 3; ++g) {
                float sx = 0.f, sh = 0.f;
#pragma unroll
                for (int kw2 = 0; kw2 < 4; ++kw2) {
                    sx += scr[((0 + g) * 4 + kw2) * 256 + eidx];
                    sh += scr[((3 + g) * 4 + kw2) * 256 + eidx];
                }
                AX[g] = sx;
                AH[g] = sh;
            }
            AX[0] += gx0; AX[1] += gx1; AX[2] += gx2;
            AH[0] += bh0; AH[1] += bh1; AH[2] += bh2;
            float rr = sigmf(AX[0] + AH[0]);
            float zz = sigmf(AX[1] + AH[1]);
            float nn = tanh_fast(AX[2] + rr * AH[2]);
            h_hist[(size_t)t * 32768 + (size_t)bb_c * 512 + d_c] =
                (1.0f - zz) * nn + zz * hpv;
        }
        flag_bar(garr, grel, u, 32, (uint)(t * 4 + 1));

        // ---- P2: target a-slice q*128 from full h[b] (register Wq) ----
        scr[tid] = h_hist[(size_t)t * 32768 + (size_t)b * 512 + tid];
        __syncthreads();
        {
            float acc = 0.f;
#pragma unroll
            for (int i = 0; i < 64; ++i) {
                uint w = wqreg[i];
                acc = fmaf(bfl(w), scr[(dq_p2 * 64 + i) * 2 + 0],
                           fmaf(bfh(w), scr[(dq_p2 * 64 + i) * 2 + 1], acc));
            }
            scr[512 + tid] = acc;
        }
        __syncthreads();
        if (tid < 128)
            scr[1024 + tid] = scr[512 + tid] + scr[640 + tid] +
                              scr[768 + tid] + scr[896 + tid];
        __syncthreads();

        // ---- P3: partial energy over a-slice, all 256 s ----
        {
            int s = tid & 255, hf = tid >> 8;
            int sw = (s ^ (s >> 3)) & 7;
            float acc = 0.f;
#pragma unroll
            for (int c8 = 0; c8 < 8; ++c8) {
                int ch = hf * 8 + c8;
                uint4 pv = *(const uint4*)&preT[s * 128 + ((ch ^ sw) << 3)];
                int ab = ch * 8;
                acc += svatt[ab + 0] * tanh_fast(bfl(pv.x) + scr[1024 + ab + 0]);
                acc += svatt[ab + 1] * tanh_fast(bfh(pv.x) + scr[1024 + ab + 1]);
                acc += svatt[ab + 2] * tanh_fast(bfl(pv.y) + scr[1024 + ab + 2]);
                acc += svatt[ab + 3] * tanh_fast(bfh(pv.y) + scr[1024 + ab + 3]);
                acc += svatt[ab + 4] * tanh_fast(bfl(pv.z) + scr[1024 + ab + 4]);
                acc += svatt[ab + 5] * tanh_fast(bfh(pv.z) + scr[1024 + ab + 5]);
                acc += svatt[ab + 6] * tanh_fast(bfl(pv.w) + scr[1024 + ab + 6]);
                acc += svatt[ab + 7] * tanh_fast(bfh(pv.w) + scr[1024 + ab + 7]);
            }
            scr[1280 + tid] = acc;
        }
        __syncthreads();
        if (tid < 256)
            pe_buf[((size_t)t * 64 + b) * 1024 + q * 256 + tid] =
                scr[1280 + tid] + scr[1536 + tid];
        flag_bar(carr, crel, q, 4, (uint)(t * 4 + 2));

        // ---- P4: softmax (redundant per cluster block) + ctx GEMV e-slice ----
        {
            int s2 = tid & 255;
            const float* peb = pe_buf + ((size_t)t * 64 + b) * 1024;
            float e = peb[s2] + peb[256 + s2] + peb[512 + s2] + peb[768 + s2];
            float mk = smask[s2];
            e = e * (1.0f - mk) + mk * (-1e6f);
            float mx = e;
#pragma unroll
            for (int off = 1; off < 64; off <<= 1) mx = fmaxf(mx, __shfl_xor(mx, off));
            if (lane == 0) scr[3072 + wid] = mx;
            __syncthreads();
            mx = scr[3072];
#pragma unroll
            for (int w2 = 1; w2 < 8; ++w2) mx = fmaxf(mx, scr[3072 + w2]);
            float ex = __expf(e - mx);
            float sm = ex;
#pragma unroll
            for (int off = 1; off < 64; off <<= 1) sm += __shfl_xor(sm, off);
            if (lane == 0) scr[3080 + wid] = sm;
            __syncthreads();
            sm = scr[3080] + scr[3081] + scr[3082] + scr[3083];
            float sc = ex / sm;
            scr[1792 + s2] = sc;
            if (q == 0 && tid < 256) cout[((size_t)t * 64 + b) * 256 + tid] = sc;
        }
        __syncthreads();
        {
            // ctx GEMV: e-pair per thread (b32 LDS reads), 8 s-chunks of 32
            int e2 = tid & 63, sq = tid >> 6;
            float acc0 = 0.f, acc1 = 0.f;
#pragma unroll 8
            for (int i = 0; i < 32; ++i) {
                int ss = sq * 32 + i;
                uint cv = *(const uint*)&ctxT[ss * 128 + e2 * 2];
                float sc = scr[1792 + ss];
                acc0 = fmaf(sc, bfl(cv), acc0);
                acc1 = fmaf(sc, bfh(cv), acc1);
            }
            scr[2048 + sq * 128 + e2 * 2 + 0] = acc0;
            scr[2048 + sq * 128 + e2 * 2 + 1] = acc1;
        }
        __syncthreads();
        if (tid < 128) {
            float val = 0.f;
#pragma unroll
            for (int s8 = 0; s8 < 8; ++s8) val += scr[2048 + s8 * 128 + tid];
            ctx_hist[(size_t)t * 32768 + (size_t)b * 512 + q * 128 + tid] = val;
        }

        // ---- split-phase final group barrier ----
        __syncthreads();
        if (tid == 0) {
            asm volatile("s_waitcnt vmcnt(0) lgkmcnt(0)" ::: "memory");
            __hip_atomic_store(garr + u, (uint)(t * 4 + 3), __ATOMIC_RELAXED,
                               __HIP_MEMORY_SCOPE_AGENT);
        }
        if (t < 31) {
            // overlap: prefetch next-step globals + stage h-half (h[t] already
            // globally visible since bar1 of this step)
            if (tid < 128) {
                const float* gp = gxe + ((size_t)(t + 1) * 64 + bb_c) * 1536 + d_c;
                gx0 = gp[0]; gx1 = gp[512]; gx2 = gp[1024];
                hpv = h_hist[(size_t)t * 32768 + (size_t)bb_c * 512 + d_c];
            }
            int c = tid & 63, row = tid >> 6;
            int bb = r + row * 8;
            const float* sp = h_hist + (size_t)t * 32768 + (size_t)bb * 512 + c * 8;
            float4 v0 = *(const float4*)sp, v1 = *(const float4*)(sp + 4);
            uint4 p1;
            p1.x = pk2(v0.x, v0.y); p1.y = pk2(v0.z, v0.w);
            p1.z = pk2(v1.x, v1.y); p1.w = pk2(v1.z, v1.w);
            *(uint4*)((char*)scr + 8192 + row * 1024 + ((c ^ row) << 4)) = p1;
        }
        if (u == 0) {
            if (tid > 0 && tid < 32) {
                while (__hip_atomic_load(garr + tid, __ATOMIC_RELAXED,
                                         __HIP_MEMORY_SCOPE_AGENT) < (uint)(t * 4 + 3)) {}
            }
            if (tid == 0)
                __hip_atomic_store(grel, (uint)(t * 4 + 3), __ATOMIC_RELAXED,
                                   __HIP_MEMORY_SCOPE_AGENT);
        } else {
            if (tid == 0) {
                while (__hip_atomic_load(grel, __ATOMIC_RELAXED,
                                         __HIP_MEMORY_SCOPE_AGENT) < (uint)(t * 4 + 3)) {}
            }
        }
        __syncthreads();
        if (t < 31) {
            // post-wait: stage ctx-half (needed ctx from other clusters)
            int c = tid & 63, row = tid >> 6;
            int bb = r + row * 8;
            const float* sp = ctx_hist + (size_t)t * 32768 + (size_t)bb * 512 + c * 8;
            float4 v0 = *(const float4*)sp, v1 = *(const float4*)(sp + 4);
            uint4 p0;
            p0.x = pk2(v0.x, v0.y); p0.y = pk2(v0.z, v0.w);
            p0.z = pk2(v1.x, v1.y); p0.w = pk2(v1.z, v1.w);
            *(uint4*)((char*)scr + row * 1024 + ((c ^ row) << 4)) = p0;
        }
        __syncthreads();
    }
}

// ================= fused post: readout GEMM | copy gate | tail copies =========
__global__ __launch_bounds__(256) void k_post(
    const float* __restrict__ emb_t, const int* __restrict__ ids,
    const float* __restrict__ h_hist, const float* __restrict__ ctx_hist,
    const float* __restrict__ W_read, const float* __restrict__ b_read,
    const float* __restrict__ W_copy, const float* __restrict__ b_copy,
    float* __restrict__ out)
{
    __shared__ __align__(16) ushort Ab[4 * 16 * 32];
    __shared__ __align__(16) ushort Bb[64 * 32];
    __shared__ int rid[64];
    const int bid = blockIdx.x;
    const int tid = threadIdx.x;
    if (bid < 256) {
        mgemm_body<2, 4>(emb_t, h_hist, ctx_hist, ids, W_read, b_read,
                         (void*)out, 1536, 1536, bid & 31, bid >> 5, Ab, Bb, rid);
    } else if (bid < 768) {
        const int lane = tid & 63;
        const int tb = (bid - 256) * 4 + (tid >> 6);
        const float* hp = h_hist + (size_t)tb * DD;
        const float* cp = ctx_hist + (size_t)tb * DD;
        float acc = 0.f;
#pragma unroll
        for (int jj = 0; jj < 8; ++jj) {
            int k = lane + 64 * jj;
            acc = fmaf(hp[k], W_copy[k], acc);
            acc = fmaf(cp[k], W_copy[512 + k], acc);
        }
#pragma unroll
        for (int off = 1; off < 64; off <<= 1) acc += __shfl_xor(acc, off);
        if (lane == 0) out[1048576 + tb] = sigmf(acc + b_copy[0]);
    } else {
        int idx = (bid - 768) * 256 + tid;
        if (idx < 32768) {
            out[1050624 + idx] = h_hist[31 * 32768 + idx];
        } else if (idx < 49152) {
            int i2 = idx - 32768;
            out[1083392 + i2] = out[524288 + 507904 + i2];
        } else {
            int i2 = idx - 49152;
            out[1099776 + i2] = ctx_hist[31 * 32768 + i2];
        }
    }
}

extern "C" void kernel_launch(void* const* d_in, const int* in_sizes, int n_in,
                              void* d_out, int out_size, void* d_ws, size_t ws_size,
                              hipStream_t stream)
{
    (void)in_sizes; (void)n_in; (void)out_size; (void)ws_size;
    const int*   ids      = (const int*)d_in[0];
    const float* hidden   = (const float*)d_in[1];
    const float* context  = (const float*)d_in[2];
    const float* mask     = (const float*)d_in[3];
    const float* init_att = (const float*)d_in[4];
    const float* emb_t    = (const float*)d_in[5];
    const float* W_ih     = (const float*)d_in[6];
    const float* W_hh     = (const float*)d_in[7];
    const float* b_ih     = (const float*)d_in[8];
    const float* b_hh     = (const float*)d_in[9];
    const float* W_pre    = (const float*)d_in[10];
    const float* b_pre    = (const float*)d_in[11];
    const float* W_q      = (const float*)d_in[12];
    const float* v_att    = (const float*)d_in[13];
    const float* W_copy   = (const float*)d_in[14];
    const float* b_copy   = (const float*)d_in[15];
    const float* W_read   = (const float*)d_in[16];
    const float* b_read   = (const float*)d_in[17];
    float* out = (float*)d_out;
    float* ws = (float*)d_ws;

    ushort* preb    = (ushort*)ws;
    float* gxe      = ws + 4194304;
    float* h_hist   = ws + 7340032;
    float* ctx_hist = ws + 8388608;
    float* pe_buf   = ws + 9437184;
    uint* Wpk       = (uint*)(ws + 11534336);
    uint* WqT       = (uint*)(ws + 12320768);
    uint* cnt       = (uint*)(ws + 12451840);
    float* cout     = out + 524288;

    k_prep<<<5377, 256, 0, stream>>>(context, emb_t, ids, W_ih, W_hh, W_q, W_pre,
                                     b_pre, b_ih, preb, gxe, Wpk, WqT, cnt);
    {
        void* args[] = {
            (void*)&gxe, (void*)&hidden, (void*)&init_att, (void*)&context,
            (void*)&mask, (void*)&v_att, (void*)&b_hh, (void*)&preb,
            (void*)&Wpk, (void*)&WqT,
            (void*)&h_hist, (void*)&ctx_hist, (void*)&pe_buf, (void*)&cnt,
            (void*)&cout
        };
        hipLaunchCooperativeKernel((void*)k_steps, dim3(256), dim3(512), args, 0,
                                   stream);
    }
    k_post<<<1088, 256, 0, stream>>>(emb_t, ids, h_hist, ctx_hist, W_read, b_read,
                                     W_copy, b_copy, out);
}